// Round 1
// baseline (570.945 us; speedup 1.0000x reference)
//
#include <hip/hip_runtime.h>
#include <hip/hip_bf16.h>

#define N_NODES 50000
#define N_GRAPHS 64

// ---------------- CSR build ----------------

__global__ void count_kernel(const int* __restrict__ dst, int* __restrict__ cnt, int ne) {
    int e = blockIdx.x * 256 + threadIdx.x;
    if (e < ne) atomicAdd(&cnt[dst[e]], 1);
}

__global__ void dinv_kernel(const int* __restrict__ cnt, float* __restrict__ dinv, int n) {
    int i = blockIdx.x * 256 + threadIdx.x;
    if (i < n) dinv[i] = rsqrtf((float)cnt[i] + 1.0f);   // deg = indeg + self-loop
}

__global__ void scan_kernel(const int* __restrict__ cnt, int* __restrict__ row_ptr, int n) {
    __shared__ int wsum[16];
    __shared__ int carry_s;
    int t = threadIdx.x;
    int lane = t & 63, w = t >> 6;
    if (t == 0) carry_s = 0;
    __syncthreads();
    for (int base = 0; base < n; base += 1024) {
        int i = base + t;
        int v = (i < n) ? cnt[i] : 0;
        int x = v;
        #pragma unroll
        for (int d = 1; d < 64; d <<= 1) {
            int y = __shfl_up(x, d, 64);
            if (lane >= d) x += y;
        }
        if (lane == 63) wsum[w] = x;
        __syncthreads();
        if (t < 16) {
            int s = wsum[t];
            #pragma unroll
            for (int d = 1; d < 16; d <<= 1) {
                int y = __shfl_up(s, d, 16);
                if (t >= d) s += y;
            }
            wsum[t] = s;
        }
        __syncthreads();
        int base_off = carry_s + (w > 0 ? wsum[w - 1] : 0);
        if (i < n) row_ptr[i] = base_off + x - v;   // exclusive
        int tile_total = wsum[15];
        __syncthreads();
        if (t == 0) carry_s += tile_total;
        __syncthreads();
    }
    if (t == 0) row_ptr[n] = carry_s;
}

__global__ void copy_int_kernel(const int* __restrict__ a, int* __restrict__ b, int n) {
    int i = blockIdx.x * 256 + threadIdx.x;
    if (i < n) b[i] = a[i];
}

__global__ void fill_kernel(const int* __restrict__ src, const int* __restrict__ dst,
                            const float* __restrict__ dinv, int* __restrict__ cur,
                            int* __restrict__ col, float* __restrict__ val, int ne) {
    int e = blockIdx.x * 256 + threadIdx.x;
    if (e < ne) {
        int s = src[e], d = dst[e];
        int p = atomicAdd(&cur[d], 1);
        col[p] = s;
        val[p] = dinv[s] * dinv[d];
    }
}

// ---------------- dense matmul: out[n,128] = A[n,128] @ W[128,128] ----------------

__global__ __launch_bounds__(256) void matmul128_kernel(const float* __restrict__ A,
                                                        const float* __restrict__ W,
                                                        float* __restrict__ out, int n) {
    __shared__ float Ws[128 * 128];
    int t = threadIdx.x;
    #pragma unroll
    for (int i = 0; i < 16; ++i) {
        int idx = (i * 256 + t) * 4;
        *(float4*)&Ws[idx] = *(const float4*)&W[idx];
    }
    __syncthreads();

    int tx = t & 15, ty = t >> 4;       // tx: col group (8 cols), ty: row group (4 rows)
    int r0 = blockIdx.x * 64 + ty * 4;
    int c0 = tx * 8;

    float acc[4][8];
    #pragma unroll
    for (int r = 0; r < 4; ++r)
        #pragma unroll
        for (int c = 0; c < 8; ++c) acc[r][c] = 0.f;

    const float* a0 = A + (size_t)min(r0 + 0, n - 1) * 128;
    const float* a1 = A + (size_t)min(r0 + 1, n - 1) * 128;
    const float* a2 = A + (size_t)min(r0 + 2, n - 1) * 128;
    const float* a3 = A + (size_t)min(r0 + 3, n - 1) * 128;

    for (int k = 0; k < 128; k += 4) {
        float4 va[4];
        va[0] = *(const float4*)(a0 + k);
        va[1] = *(const float4*)(a1 + k);
        va[2] = *(const float4*)(a2 + k);
        va[3] = *(const float4*)(a3 + k);
        #pragma unroll
        for (int kk = 0; kk < 4; ++kk) {
            float4 w0 = *(const float4*)&Ws[(k + kk) * 128 + c0];
            float4 w1 = *(const float4*)&Ws[(k + kk) * 128 + c0 + 4];
            #pragma unroll
            for (int r = 0; r < 4; ++r) {
                float av = (kk == 0) ? va[r].x : (kk == 1) ? va[r].y : (kk == 2) ? va[r].z : va[r].w;
                acc[r][0] += av * w0.x; acc[r][1] += av * w0.y;
                acc[r][2] += av * w0.z; acc[r][3] += av * w0.w;
                acc[r][4] += av * w1.x; acc[r][5] += av * w1.y;
                acc[r][6] += av * w1.z; acc[r][7] += av * w1.w;
            }
        }
    }
    #pragma unroll
    for (int r = 0; r < 4; ++r) {
        int row = r0 + r;
        if (row < n) {
            *(float4*)&out[(size_t)row * 128 + c0]     = make_float4(acc[r][0], acc[r][1], acc[r][2], acc[r][3]);
            *(float4*)&out[(size_t)row * 128 + c0 + 4] = make_float4(acc[r][4], acc[r][5], acc[r][6], acc[r][7]);
        }
    }
}

// ---------------- aggregation: out[i] = elu( sum_e val[e]*h[col[e]] + dinv[i]^2*h[i] + b ) ----------------

__global__ __launch_bounds__(256) void aggregate_kernel(const float* __restrict__ h,
                                                        const int* __restrict__ row_ptr,
                                                        const int* __restrict__ col,
                                                        const float* __restrict__ val,
                                                        const float* __restrict__ dinv,
                                                        const float* __restrict__ bias,
                                                        float* __restrict__ out, int n) {
    int node = blockIdx.x * 4 + (threadIdx.x >> 6);
    if (node >= n) return;
    int lane = threadIdx.x & 63;

    int beg = row_ptr[node], end = row_ptr[node + 1];
    float di = dinv[node];
    float2 hv = *(const float2*)&h[(size_t)node * 128 + lane * 2];
    float sx = di * di * hv.x, sy = di * di * hv.y;

    for (int e = beg; e < end; ++e) {
        int s = col[e];
        float wv = val[e];
        float2 v = *(const float2*)&h[(size_t)s * 128 + lane * 2];
        sx += wv * v.x;
        sy += wv * v.y;
    }
    float2 b = *(const float2*)&bias[lane * 2];
    sx += b.x; sy += b.y;
    sx = sx > 0.f ? sx : expm1f(sx);
    sy = sy > 0.f ? sy : expm1f(sy);
    *(float2*)&out[(size_t)node * 128 + lane * 2] = make_float2(sx, sy);
}

// ---------------- mean pool per graph (batch sorted) ----------------

__global__ __launch_bounds__(512) void pool_kernel(const float* __restrict__ act,
                                                   const int* __restrict__ batch,
                                                   float* __restrict__ pooled, int n) {
    __shared__ float red[4][128];
    int g = blockIdx.x;
    int t = threadIdx.x;
    int f = t & 127, rr = t >> 7;

    int lo = 0, hi = n;
    while (lo < hi) { int m = (lo + hi) >> 1; if (batch[m] < g) lo = m + 1; else hi = m; }
    int start = lo;
    hi = n;
    while (lo < hi) { int m = (lo + hi) >> 1; if (batch[m] < g + 1) lo = m + 1; else hi = m; }
    int end = lo;

    float acc = 0.f;
    for (int i = start + rr; i < end; i += 4) acc += act[(size_t)i * 128 + f];
    red[rr][f] = acc;
    __syncthreads();
    if (rr == 0) {
        float s = red[0][f] + red[1][f] + red[2][f] + red[3][f];
        int c = end - start;
        pooled[g * 128 + f] = (c > 0) ? s / (float)c : 0.f;
    }
}

// ---------------- final linear: out[g] = pooled[g] @ Wl + bl ----------------

__global__ __launch_bounds__(128) void linear_kernel(const float* __restrict__ pooled,
                                                     const float* __restrict__ Wl,
                                                     const float* __restrict__ bl,
                                                     float* __restrict__ out) {
    __shared__ float p[128];
    int g = blockIdx.x, t = threadIdx.x;
    p[t] = pooled[g * 128 + t];
    __syncthreads();
    float acc = bl[t];
    for (int k = 0; k < 128; ++k) acc += p[k] * Wl[k * 128 + t];
    out[g * 128 + t] = acc;
}

// ---------------- launch ----------------

extern "C" void kernel_launch(void* const* d_in, const int* in_sizes, int n_in,
                              void* d_out, int out_size, void* d_ws, size_t ws_size,
                              hipStream_t stream) {
    const float* x     = (const float*)d_in[0];
    const int*   ei    = (const int*)d_in[1];
    const int*   batch = (const int*)d_in[2];
    const float* W1 = (const float*)d_in[3];
    const float* b1 = (const float*)d_in[4];
    const float* W2 = (const float*)d_in[5];
    const float* b2 = (const float*)d_in[6];
    const float* W3 = (const float*)d_in[7];
    const float* b3 = (const float*)d_in[8];
    const float* Wl = (const float*)d_in[9];
    const float* bl = (const float*)d_in[10];
    float* out = (float*)d_out;

    const int N_ = N_NODES;
    const int E_ = in_sizes[1] / 2;
    const int G_ = N_GRAPHS;
    const int* src = ei;
    const int* dst = ei + E_;

    char* ws = (char*)d_ws;
    size_t off = 0;
    auto alloc = [&](size_t bytes) -> char* {
        char* p = ws + off;
        off += (bytes + 255) & ~(size_t)255;
        return p;
    };
    int*   cnt    = (int*)  alloc((size_t)N_ * 4);
    float* dinv   = (float*)alloc((size_t)N_ * 4);
    int*   rowptr = (int*)  alloc((size_t)(N_ + 1) * 4);
    int*   cur    = (int*)  alloc((size_t)N_ * 4);
    int*   col    = (int*)  alloc((size_t)E_ * 4);
    float* val    = (float*)alloc((size_t)E_ * 4);
    float* hbuf   = (float*)alloc((size_t)N_ * 128 * 4);
    float* act    = (float*)alloc((size_t)N_ * 128 * 4);
    float* pooled = (float*)alloc((size_t)G_ * 128 * 4);
    (void)ws_size;

    hipMemsetAsync(cnt, 0, (size_t)N_ * 4, stream);
    count_kernel<<<(E_ + 255) / 256, 256, 0, stream>>>(dst, cnt, E_);
    dinv_kernel<<<(N_ + 255) / 256, 256, 0, stream>>>(cnt, dinv, N_);
    scan_kernel<<<1, 1024, 0, stream>>>(cnt, rowptr, N_);
    copy_int_kernel<<<(N_ + 255) / 256, 256, 0, stream>>>(rowptr, cur, N_);
    fill_kernel<<<(E_ + 255) / 256, 256, 0, stream>>>(src, dst, dinv, cur, col, val, E_);

    int mmblocks = (N_ + 63) / 64;
    int agblocks = (N_ + 3) / 4;

    matmul128_kernel<<<mmblocks, 256, 0, stream>>>(x, W1, hbuf, N_);
    aggregate_kernel<<<agblocks, 256, 0, stream>>>(hbuf, rowptr, col, val, dinv, b1, act, N_);
    matmul128_kernel<<<mmblocks, 256, 0, stream>>>(act, W2, hbuf, N_);
    aggregate_kernel<<<agblocks, 256, 0, stream>>>(hbuf, rowptr, col, val, dinv, b2, act, N_);
    matmul128_kernel<<<mmblocks, 256, 0, stream>>>(act, W3, hbuf, N_);
    aggregate_kernel<<<agblocks, 256, 0, stream>>>(hbuf, rowptr, col, val, dinv, b3, act, N_);

    pool_kernel<<<G_, 512, 0, stream>>>(act, batch, pooled, N_);
    linear_kernel<<<G_, 128, 0, stream>>>(pooled, Wl, bl, out);
}

// Round 2
// 539.719 us; speedup vs baseline: 1.0579x; 1.0579x over previous
//
#include <hip/hip_runtime.h>
#include <hip/hip_bf16.h>

#define N_NODES 50000
#define N_GRAPHS 64
#define POOL_CHUNK 128

// ---------------- helpers ----------------

__device__ inline unsigned short f2bf(float x) {
    unsigned u = __float_as_uint(x);
    unsigned rounding = 0x7fffu + ((u >> 16) & 1u);
    return (unsigned short)((u + rounding) >> 16);
}
__device__ inline unsigned pack_bf2(float a, float b) {
    return (unsigned)f2bf(a) | ((unsigned)f2bf(b) << 16);
}

// ---------------- CSR build ----------------

__global__ void count_kernel(const int* __restrict__ dst, int* __restrict__ cnt, int ne) {
    int e = blockIdx.x * 256 + threadIdx.x;
    if (e < ne) atomicAdd(&cnt[dst[e]], 1);
}

__global__ void dinv_kernel(const int* __restrict__ cnt, float* __restrict__ dinv, int n) {
    int i = blockIdx.x * 256 + threadIdx.x;
    if (i < n) dinv[i] = rsqrtf((float)cnt[i] + 1.0f);   // deg = indeg + self-loop
}

__global__ void scan_kernel(const int* __restrict__ cnt, int* __restrict__ row_ptr,
                            int* __restrict__ cur, int n) {
    __shared__ int wsum[16];
    __shared__ int carry_s;
    int t = threadIdx.x;
    int lane = t & 63, w = t >> 6;
    if (t == 0) carry_s = 0;
    __syncthreads();
    for (int base = 0; base < n; base += 1024) {
        int i = base + t;
        int v = (i < n) ? cnt[i] : 0;
        int x = v;
        #pragma unroll
        for (int d = 1; d < 64; d <<= 1) {
            int y = __shfl_up(x, d, 64);
            if (lane >= d) x += y;
        }
        if (lane == 63) wsum[w] = x;
        __syncthreads();
        if (t < 16) {
            int s = wsum[t];
            #pragma unroll
            for (int d = 1; d < 16; d <<= 1) {
                int y = __shfl_up(s, d, 16);
                if (t >= d) s += y;
            }
            wsum[t] = s;
        }
        __syncthreads();
        int base_off = carry_s + (w > 0 ? wsum[w - 1] : 0);
        if (i < n) {
            int ex = base_off + x - v;    // exclusive
            row_ptr[i] = ex;
            cur[i] = ex;
        }
        int tile_total = wsum[15];
        __syncthreads();
        if (t == 0) carry_s += tile_total;
        __syncthreads();
    }
    if (t == 0) row_ptr[n] = carry_s;
}

__global__ void fill_kernel(const int* __restrict__ src, const int* __restrict__ dst,
                            const float* __restrict__ dinv, int* __restrict__ cur,
                            int* __restrict__ col, float* __restrict__ val, int ne) {
    int e = blockIdx.x * 256 + threadIdx.x;
    if (e < ne) {
        int s = src[e], d = dst[e];
        int p = atomicAdd(&cur[d], 1);
        col[p] = s;
        val[p] = dinv[s] * dinv[d];
    }
}

// ---------------- dense matmul: hb[n,128](bf16) = A[n,128](f32) @ W[128,128](f32) ----------------

__global__ __launch_bounds__(256) void matmul128_kernel(const float* __restrict__ A,
                                                        const float* __restrict__ W,
                                                        unsigned* __restrict__ hb, int n) {
    __shared__ float Ws[128 * 128];
    int t = threadIdx.x;
    #pragma unroll
    for (int i = 0; i < 16; ++i) {
        int idx = (i * 256 + t) * 4;
        *(float4*)&Ws[idx] = *(const float4*)&W[idx];
    }
    __syncthreads();

    int tx = t & 15, ty = t >> 4;       // tx: col group (8 cols), ty: row group (4 rows)
    int r0 = blockIdx.x * 64 + ty * 4;
    int c0 = tx * 8;

    float acc[4][8];
    #pragma unroll
    for (int r = 0; r < 4; ++r)
        #pragma unroll
        for (int c = 0; c < 8; ++c) acc[r][c] = 0.f;

    const float* a0 = A + (size_t)min(r0 + 0, n - 1) * 128;
    const float* a1 = A + (size_t)min(r0 + 1, n - 1) * 128;
    const float* a2 = A + (size_t)min(r0 + 2, n - 1) * 128;
    const float* a3 = A + (size_t)min(r0 + 3, n - 1) * 128;

    for (int k = 0; k < 128; k += 4) {
        float4 va[4];
        va[0] = *(const float4*)(a0 + k);
        va[1] = *(const float4*)(a1 + k);
        va[2] = *(const float4*)(a2 + k);
        va[3] = *(const float4*)(a3 + k);
        #pragma unroll
        for (int kk = 0; kk < 4; ++kk) {
            float4 w0 = *(const float4*)&Ws[(k + kk) * 128 + c0];
            float4 w1 = *(const float4*)&Ws[(k + kk) * 128 + c0 + 4];
            #pragma unroll
            for (int r = 0; r < 4; ++r) {
                float av = (kk == 0) ? va[r].x : (kk == 1) ? va[r].y : (kk == 2) ? va[r].z : va[r].w;
                acc[r][0] += av * w0.x; acc[r][1] += av * w0.y;
                acc[r][2] += av * w0.z; acc[r][3] += av * w0.w;
                acc[r][4] += av * w1.x; acc[r][5] += av * w1.y;
                acc[r][6] += av * w1.z; acc[r][7] += av * w1.w;
            }
        }
    }
    #pragma unroll
    for (int r = 0; r < 4; ++r) {
        int row = r0 + r;
        if (row < n) {
            uint4 pk;
            pk.x = pack_bf2(acc[r][0], acc[r][1]);
            pk.y = pack_bf2(acc[r][2], acc[r][3]);
            pk.z = pack_bf2(acc[r][4], acc[r][5]);
            pk.w = pack_bf2(acc[r][6], acc[r][7]);
            *(uint4*)&hb[(size_t)row * 64 + (c0 >> 1)] = pk;
        }
    }
}

// ---------------- aggregation: out = elu( A_norm @ h + b ), h in bf16 ----------------

__global__ __launch_bounds__(256) void aggregate_kernel(const unsigned* __restrict__ hb,
                                                        const int* __restrict__ row_ptr,
                                                        const int* __restrict__ col,
                                                        const float* __restrict__ val,
                                                        const float* __restrict__ dinv,
                                                        const float* __restrict__ bias,
                                                        float* __restrict__ out, int n) {
    int node = blockIdx.x * 4 + (threadIdx.x >> 6);
    if (node >= n) return;
    int lane = threadIdx.x & 63;

    int beg = row_ptr[node], end = row_ptr[node + 1];
    float di = dinv[node];
    unsigned hv = hb[(size_t)node * 64 + lane];
    float sx = di * di * __uint_as_float(hv << 16);
    float sy = di * di * __uint_as_float(hv & 0xffff0000u);

    for (int e = beg; e < end; ++e) {
        int s = col[e];
        float wv = val[e];
        unsigned v = hb[(size_t)s * 64 + lane];
        sx += wv * __uint_as_float(v << 16);
        sy += wv * __uint_as_float(v & 0xffff0000u);
    }
    float2 b = *(const float2*)&bias[lane * 2];
    sx += b.x; sy += b.y;
    sx = sx > 0.f ? sx : expm1f(sx);
    sy = sy > 0.f ? sy : expm1f(sy);
    *(float2*)&out[(size_t)node * 128 + lane * 2] = make_float2(sx, sy);
}

// ---------------- mean pool: chunked partial sums + atomic flush ----------------

__global__ __launch_bounds__(128) void pool_partial_kernel(const float* __restrict__ act,
                                                           const int* __restrict__ batch,
                                                           float* __restrict__ pooled, int n) {
    int f = threadIdx.x;
    int start = blockIdx.x * POOL_CHUNK;
    if (start >= n) return;
    int end = min(start + POOL_CHUNK, n);

    float local = 0.f;
    int gprev = batch[start];
    for (int i = start; i < end; ++i) {
        int g = batch[i];
        if (g != gprev) {
            atomicAdd(&pooled[gprev * 128 + f], local);
            local = 0.f;
            gprev = g;
        }
        local += act[(size_t)i * 128 + f];
    }
    atomicAdd(&pooled[gprev * 128 + f], local);
}

// ---------------- final: out[g] = (pooled[g]/cnt) @ Wl + bl ----------------

__global__ __launch_bounds__(128) void linear_kernel(const float* __restrict__ pooled,
                                                     const int* __restrict__ batch,
                                                     const float* __restrict__ Wl,
                                                     const float* __restrict__ bl,
                                                     float* __restrict__ out, int n) {
    __shared__ float p[128];
    int g = blockIdx.x, t = threadIdx.x;

    int lo = 0, hi = n;
    while (lo < hi) { int m = (lo + hi) >> 1; if (batch[m] < g) lo = m + 1; else hi = m; }
    int s0 = lo;
    hi = n;
    while (lo < hi) { int m = (lo + hi) >> 1; if (batch[m] < g + 1) lo = m + 1; else hi = m; }
    int e0 = lo;
    float cntf = (float)max(e0 - s0, 1);

    p[t] = pooled[g * 128 + t] / cntf;
    __syncthreads();
    float acc = bl[t];
    for (int k = 0; k < 128; ++k) acc += p[k] * Wl[k * 128 + t];
    out[g * 128 + t] = acc;
}

// ---------------- launch ----------------

extern "C" void kernel_launch(void* const* d_in, const int* in_sizes, int n_in,
                              void* d_out, int out_size, void* d_ws, size_t ws_size,
                              hipStream_t stream) {
    const float* x     = (const float*)d_in[0];
    const int*   ei    = (const int*)d_in[1];
    const int*   batch = (const int*)d_in[2];
    const float* W1 = (const float*)d_in[3];
    const float* b1 = (const float*)d_in[4];
    const float* W2 = (const float*)d_in[5];
    const float* b2 = (const float*)d_in[6];
    const float* W3 = (const float*)d_in[7];
    const float* b3 = (const float*)d_in[8];
    const float* Wl = (const float*)d_in[9];
    const float* bl = (const float*)d_in[10];
    float* out = (float*)d_out;

    const int N_ = N_NODES;
    const int E_ = in_sizes[1] / 2;
    const int G_ = N_GRAPHS;
    const int* src = ei;
    const int* dst = ei + E_;

    char* ws = (char*)d_ws;
    size_t off = 0;
    auto alloc = [&](size_t bytes) -> char* {
        char* p = ws + off;
        off += (bytes + 255) & ~(size_t)255;
        return p;
    };
    int*      cnt    = (int*)     alloc((size_t)N_ * 4);
    float*    dinv   = (float*)   alloc((size_t)N_ * 4);
    int*      rowptr = (int*)     alloc((size_t)(N_ + 1) * 4);
    int*      cur    = (int*)     alloc((size_t)N_ * 4);
    int*      col    = (int*)     alloc((size_t)E_ * 4);
    float*    val    = (float*)   alloc((size_t)E_ * 4);
    unsigned* hbuf   = (unsigned*)alloc((size_t)N_ * 64 * 4);   // bf16 h, packed pairs
    float*    act    = (float*)   alloc((size_t)N_ * 128 * 4);
    float*    pooled = (float*)   alloc((size_t)G_ * 128 * 4);
    (void)ws_size;

    hipMemsetAsync(cnt, 0, (size_t)N_ * 4, stream);
    hipMemsetAsync(pooled, 0, (size_t)G_ * 128 * 4, stream);

    count_kernel<<<(E_ + 255) / 256, 256, 0, stream>>>(dst, cnt, E_);
    dinv_kernel<<<(N_ + 255) / 256, 256, 0, stream>>>(cnt, dinv, N_);
    scan_kernel<<<1, 1024, 0, stream>>>(cnt, rowptr, cur, N_);
    fill_kernel<<<(E_ + 255) / 256, 256, 0, stream>>>(src, dst, dinv, cur, col, val, E_);

    int mmblocks = (N_ + 63) / 64;
    int agblocks = (N_ + 3) / 4;

    matmul128_kernel<<<mmblocks, 256, 0, stream>>>(x, W1, hbuf, N_);
    aggregate_kernel<<<agblocks, 256, 0, stream>>>(hbuf, rowptr, col, val, dinv, b1, act, N_);
    matmul128_kernel<<<mmblocks, 256, 0, stream>>>(act, W2, hbuf, N_);
    aggregate_kernel<<<agblocks, 256, 0, stream>>>(hbuf, rowptr, col, val, dinv, b2, act, N_);
    matmul128_kernel<<<mmblocks, 256, 0, stream>>>(act, W3, hbuf, N_);
    aggregate_kernel<<<agblocks, 256, 0, stream>>>(hbuf, rowptr, col, val, dinv, b3, act, N_);

    pool_partial_kernel<<<(N_ + POOL_CHUNK - 1) / POOL_CHUNK, 128, 0, stream>>>(act, batch, pooled, N_);
    linear_kernel<<<G_, 128, 0, stream>>>(pooled, batch, Wl, bl, out, N_);
}

// Round 3
// 369.551 us; speedup vs baseline: 1.5450x; 1.4605x over previous
//
#include <hip/hip_runtime.h>
#include <hip/hip_bf16.h>

#define N_NODES 50000
#define N_GRAPHS 64
#define POOL_CHUNK 128

// ---------------- helpers ----------------

__device__ inline unsigned short f2bf(float x) {
    unsigned u = __float_as_uint(x);
    unsigned rounding = 0x7fffu + ((u >> 16) & 1u);
    return (unsigned short)((u + rounding) >> 16);
}
__device__ inline unsigned pack_bf2(float a, float b) {
    return (unsigned)f2bf(a) | ((unsigned)f2bf(b) << 16);
}

__device__ inline void fma_bf8(float (&acc)[8], uint4 v, float w) {
    acc[0] += w * __uint_as_float(v.x << 16);
    acc[1] += w * __uint_as_float(v.x & 0xffff0000u);
    acc[2] += w * __uint_as_float(v.y << 16);
    acc[3] += w * __uint_as_float(v.y & 0xffff0000u);
    acc[4] += w * __uint_as_float(v.z << 16);
    acc[5] += w * __uint_as_float(v.z & 0xffff0000u);
    acc[6] += w * __uint_as_float(v.w << 16);
    acc[7] += w * __uint_as_float(v.w & 0xffff0000u);
}

// ---------------- CSR build ----------------

__global__ void count_kernel(const int* __restrict__ dst, int* __restrict__ cnt, int ne) {
    int e = blockIdx.x * 256 + threadIdx.x;
    if (e < ne) atomicAdd(&cnt[dst[e]], 1);
}

// per-block sums of cnt (256 elems/block)
__global__ __launch_bounds__(256) void blocksum_kernel(const int* __restrict__ cnt,
                                                       int* __restrict__ bsum, int n) {
    int i = blockIdx.x * 256 + threadIdx.x;
    int t = threadIdx.x, lane = t & 63, w = t >> 6;
    int v = (i < n) ? cnt[i] : 0;
    #pragma unroll
    for (int d = 1; d < 64; d <<= 1) v += __shfl_xor(v, d, 64);
    __shared__ int ws[4];
    if (lane == 0) ws[w] = v;
    __syncthreads();
    if (t == 0) bsum[blockIdx.x] = ws[0] + ws[1] + ws[2] + ws[3];
}

// exclusive scan of block sums (nb <= 256), single block
__global__ __launch_bounds__(256) void scan_bsum_kernel(int* __restrict__ bsum, int nb) {
    __shared__ int s[256];
    int t = threadIdx.x;
    int v = (t < nb) ? bsum[t] : 0;
    s[t] = v;
    __syncthreads();
    #pragma unroll
    for (int d = 1; d < 256; d <<= 1) {
        int y = (t >= d) ? s[t - d] : 0;
        __syncthreads();
        s[t] += y;
        __syncthreads();
    }
    if (t < nb) bsum[t] = s[t] - v;   // exclusive
}

// final: rowptr/cur = global exclusive scan; dinv fused
__global__ __launch_bounds__(256) void scan_final_kernel(const int* __restrict__ cnt,
                                                         const int* __restrict__ bsum,
                                                         int* __restrict__ rowptr,
                                                         int* __restrict__ cur,
                                                         float* __restrict__ dinv,
                                                         int n, int ne) {
    int i = blockIdx.x * 256 + threadIdx.x;
    int t = threadIdx.x, lane = t & 63, w = t >> 6;
    int v = (i < n) ? cnt[i] : 0;
    int x = v;
    #pragma unroll
    for (int d = 1; d < 64; d <<= 1) {
        int y = __shfl_up(x, d, 64);
        if (lane >= d) x += y;
    }
    __shared__ int ws[4];
    if (lane == 63) ws[w] = x;
    __syncthreads();
    int woff = 0;
    #pragma unroll
    for (int k = 0; k < 4; ++k) woff += (k < w) ? ws[k] : 0;
    if (i < n) {
        int ex = bsum[blockIdx.x] + woff + x - v;
        rowptr[i] = ex;
        cur[i] = ex;
        dinv[i] = rsqrtf((float)v + 1.0f);
    }
    if (blockIdx.x == 0 && t == 0) rowptr[n] = ne;
}

__global__ void fill_kernel(const int* __restrict__ src, const int* __restrict__ dst,
                            const float* __restrict__ dinv, int* __restrict__ cur,
                            int2* __restrict__ cv, int ne) {
    int e = blockIdx.x * 256 + threadIdx.x;
    if (e < ne) {
        int s = src[e], d = dst[e];
        int p = atomicAdd(&cur[d], 1);
        cv[p] = make_int2(s, __float_as_int(dinv[s] * dinv[d]));
    }
}

// ---------------- dense matmul: hb[n,128](bf16) = A[n,128](f32) @ W[128,128](f32) ----------------

__global__ __launch_bounds__(256) void matmul128_kernel(const float* __restrict__ A,
                                                        const float* __restrict__ W,
                                                        unsigned* __restrict__ hb, int n) {
    __shared__ float Ws[128 * 128];
    int t = threadIdx.x;
    #pragma unroll
    for (int i = 0; i < 16; ++i) {
        int idx = (i * 256 + t) * 4;
        *(float4*)&Ws[idx] = *(const float4*)&W[idx];
    }
    __syncthreads();

    int tx = t & 15, ty = t >> 4;
    int r0 = blockIdx.x * 64 + ty * 4;
    int c0 = tx * 8;

    float acc[4][8];
    #pragma unroll
    for (int r = 0; r < 4; ++r)
        #pragma unroll
        for (int c = 0; c < 8; ++c) acc[r][c] = 0.f;

    const float* a0 = A + (size_t)min(r0 + 0, n - 1) * 128;
    const float* a1 = A + (size_t)min(r0 + 1, n - 1) * 128;
    const float* a2 = A + (size_t)min(r0 + 2, n - 1) * 128;
    const float* a3 = A + (size_t)min(r0 + 3, n - 1) * 128;

    for (int k = 0; k < 128; k += 4) {
        float4 va[4];
        va[0] = *(const float4*)(a0 + k);
        va[1] = *(const float4*)(a1 + k);
        va[2] = *(const float4*)(a2 + k);
        va[3] = *(const float4*)(a3 + k);
        #pragma unroll
        for (int kk = 0; kk < 4; ++kk) {
            float4 w0 = *(const float4*)&Ws[(k + kk) * 128 + c0];
            float4 w1 = *(const float4*)&Ws[(k + kk) * 128 + c0 + 4];
            #pragma unroll
            for (int r = 0; r < 4; ++r) {
                float av = (kk == 0) ? va[r].x : (kk == 1) ? va[r].y : (kk == 2) ? va[r].z : va[r].w;
                acc[r][0] += av * w0.x; acc[r][1] += av * w0.y;
                acc[r][2] += av * w0.z; acc[r][3] += av * w0.w;
                acc[r][4] += av * w1.x; acc[r][5] += av * w1.y;
                acc[r][6] += av * w1.z; acc[r][7] += av * w1.w;
            }
        }
    }
    #pragma unroll
    for (int r = 0; r < 4; ++r) {
        int row = r0 + r;
        if (row < n) {
            uint4 pk;
            pk.x = pack_bf2(acc[r][0], acc[r][1]);
            pk.y = pack_bf2(acc[r][2], acc[r][3]);
            pk.z = pack_bf2(acc[r][4], acc[r][5]);
            pk.w = pack_bf2(acc[r][6], acc[r][7]);
            *(uint4*)&hb[(size_t)row * 64 + (c0 >> 1)] = pk;
        }
    }
}

// ---------------- aggregation: out = elu( A_norm @ h + b ) ----------------
// wave = 1 node; 4 groups x 16 lanes; group g handles edges e = beg+g, beg+g+4, ...
// lane li holds features [li*8, li*8+8) as uint4 (8 bf16)

__global__ __launch_bounds__(256) void aggregate_kernel(const uint4* __restrict__ hb4,
                                                        const int* __restrict__ row_ptr,
                                                        const int2* __restrict__ cv,
                                                        const float* __restrict__ dinv,
                                                        const float* __restrict__ bias,
                                                        float* __restrict__ out, int n) {
    int node = blockIdx.x * 4 + (threadIdx.x >> 6);
    if (node >= n) return;
    int lane = threadIdx.x & 63;
    int grp = lane >> 4, li = lane & 15;

    int beg = row_ptr[node], end = row_ptr[node + 1];

    float acc[8];
    #pragma unroll
    for (int i = 0; i < 8; ++i) acc[i] = 0.f;

    if (grp == 0) {
        float di = dinv[node];
        uint4 h = hb4[(size_t)node * 16 + li];
        fma_bf8(acc, h, di * di);
    }

    int e = beg + grp;
    int2 ev;
    if (e < end) ev = cv[e];
    while (e < end) {
        int en = e + 4;
        int2 nx;
        if (en < end) nx = cv[en];
        uint4 v = hb4[(size_t)ev.x * 16 + li];
        fma_bf8(acc, v, __int_as_float(ev.y));
        ev = nx;
        e = en;
    }

    #pragma unroll
    for (int i = 0; i < 8; ++i) {
        acc[i] += __shfl_xor(acc[i], 16, 64);
        acc[i] += __shfl_xor(acc[i], 32, 64);
    }

    if (grp == 0) {
        float4 b0 = *(const float4*)&bias[li * 8];
        float4 b1 = *(const float4*)&bias[li * 8 + 4];
        float o[8];
        o[0] = acc[0] + b0.x; o[1] = acc[1] + b0.y; o[2] = acc[2] + b0.z; o[3] = acc[3] + b0.w;
        o[4] = acc[4] + b1.x; o[5] = acc[5] + b1.y; o[6] = acc[6] + b1.z; o[7] = acc[7] + b1.w;
        #pragma unroll
        for (int i = 0; i < 8; ++i) o[i] = o[i] > 0.f ? o[i] : expm1f(o[i]);
        *(float4*)&out[(size_t)node * 128 + li * 8]     = make_float4(o[0], o[1], o[2], o[3]);
        *(float4*)&out[(size_t)node * 128 + li * 8 + 4] = make_float4(o[4], o[5], o[6], o[7]);
    }
}

// ---------------- mean pool: chunked partial sums + atomic flush ----------------

__global__ __launch_bounds__(128) void pool_partial_kernel(const float* __restrict__ act,
                                                           const int* __restrict__ batch,
                                                           float* __restrict__ pooled, int n) {
    int f = threadIdx.x;
    int start = blockIdx.x * POOL_CHUNK;
    if (start >= n) return;
    int end = min(start + POOL_CHUNK, n);

    float local = 0.f;
    int gprev = batch[start];
    for (int i = start; i < end; ++i) {
        int g = batch[i];
        if (g != gprev) {
            atomicAdd(&pooled[gprev * 128 + f], local);
            local = 0.f;
            gprev = g;
        }
        local += act[(size_t)i * 128 + f];
    }
    atomicAdd(&pooled[gprev * 128 + f], local);
}

// ---------------- final: out[g] = (pooled[g]/cnt) @ Wl + bl ----------------

__global__ __launch_bounds__(128) void linear_kernel(const float* __restrict__ pooled,
                                                     const int* __restrict__ batch,
                                                     const float* __restrict__ Wl,
                                                     const float* __restrict__ bl,
                                                     float* __restrict__ out, int n) {
    __shared__ float p[128];
    int g = blockIdx.x, t = threadIdx.x;

    int lo = 0, hi = n;
    while (lo < hi) { int m = (lo + hi) >> 1; if (batch[m] < g) lo = m + 1; else hi = m; }
    int s0 = lo;
    hi = n;
    while (lo < hi) { int m = (lo + hi) >> 1; if (batch[m] < g + 1) lo = m + 1; else hi = m; }
    int e0 = lo;
    float cntf = (float)max(e0 - s0, 1);

    p[t] = pooled[g * 128 + t] / cntf;
    __syncthreads();
    float acc = bl[t];
    for (int k = 0; k < 128; ++k) acc += p[k] * Wl[k * 128 + t];
    out[g * 128 + t] = acc;
}

// ---------------- launch ----------------

extern "C" void kernel_launch(void* const* d_in, const int* in_sizes, int n_in,
                              void* d_out, int out_size, void* d_ws, size_t ws_size,
                              hipStream_t stream) {
    const float* x     = (const float*)d_in[0];
    const int*   ei    = (const int*)d_in[1];
    const int*   batch = (const int*)d_in[2];
    const float* W1 = (const float*)d_in[3];
    const float* b1 = (const float*)d_in[4];
    const float* W2 = (const float*)d_in[5];
    const float* b2 = (const float*)d_in[6];
    const float* W3 = (const float*)d_in[7];
    const float* b3 = (const float*)d_in[8];
    const float* Wl = (const float*)d_in[9];
    const float* bl = (const float*)d_in[10];
    float* out = (float*)d_out;

    const int N_ = N_NODES;
    const int E_ = in_sizes[1] / 2;
    const int G_ = N_GRAPHS;
    const int* src = ei;
    const int* dst = ei + E_;

    char* ws = (char*)d_ws;
    size_t off = 0;
    auto alloc = [&](size_t bytes) -> char* {
        char* p = ws + off;
        off += (bytes + 255) & ~(size_t)255;
        return p;
    };
    const int NB = (N_ + 255) / 256;   // 196 scan blocks

    int*      cnt    = (int*)     alloc((size_t)N_ * 4);
    float*    dinv   = (float*)   alloc((size_t)N_ * 4);
    int*      rowptr = (int*)     alloc((size_t)(N_ + 1) * 4);
    int*      cur    = (int*)     alloc((size_t)N_ * 4);
    int*      bsum   = (int*)     alloc((size_t)NB * 4);
    int2*     cv     = (int2*)    alloc((size_t)E_ * 8);
    unsigned* hbuf   = (unsigned*)alloc((size_t)N_ * 64 * 4);   // bf16 h, packed pairs
    float*    act    = (float*)   alloc((size_t)N_ * 128 * 4);
    float*    pooled = (float*)   alloc((size_t)G_ * 128 * 4);
    (void)ws_size;

    hipMemsetAsync(cnt, 0, (size_t)N_ * 4, stream);
    hipMemsetAsync(pooled, 0, (size_t)G_ * 128 * 4, stream);

    count_kernel<<<(E_ + 255) / 256, 256, 0, stream>>>(dst, cnt, E_);
    blocksum_kernel<<<NB, 256, 0, stream>>>(cnt, bsum, N_);
    scan_bsum_kernel<<<1, 256, 0, stream>>>(bsum, NB);
    scan_final_kernel<<<NB, 256, 0, stream>>>(cnt, bsum, rowptr, cur, dinv, N_, E_);
    fill_kernel<<<(E_ + 255) / 256, 256, 0, stream>>>(src, dst, dinv, cur, cv, E_);

    int mmblocks = (N_ + 63) / 64;
    int agblocks = (N_ + 3) / 4;

    matmul128_kernel<<<mmblocks, 256, 0, stream>>>(x, W1, hbuf, N_);
    aggregate_kernel<<<agblocks, 256, 0, stream>>>((const uint4*)hbuf, rowptr, cv, dinv, b1, act, N_);
    matmul128_kernel<<<mmblocks, 256, 0, stream>>>(act, W2, hbuf, N_);
    aggregate_kernel<<<agblocks, 256, 0, stream>>>((const uint4*)hbuf, rowptr, cv, dinv, b2, act, N_);
    matmul128_kernel<<<mmblocks, 256, 0, stream>>>(act, W3, hbuf, N_);
    aggregate_kernel<<<agblocks, 256, 0, stream>>>((const uint4*)hbuf, rowptr, cv, dinv, b3, act, N_);

    pool_partial_kernel<<<(N_ + POOL_CHUNK - 1) / POOL_CHUNK, 128, 0, stream>>>(act, batch, pooled, N_);
    linear_kernel<<<G_, 128, 0, stream>>>(pooled, batch, Wl, bl, out, N_);
}